// Round 5
// baseline (1567.150 us; speedup 1.0000x reference)
//
#include <hip/hip_runtime.h>
#include <math.h>

// Problem constants (fixed by reference setup_inputs)
#define N_NODES 262144      // S*T
#define SSTMT   16384
#define TT      16
#define DD      128
#define HH      3
#define HD      384         // H*D
#define EPSV    1e-5f

// ---------------------------------------------------------------------------
// stage a [32][128] fp32 tile row-major from global (row stride = 128 floats)
// ---------------------------------------------------------------------------
__device__ __forceinline__ void stage32x128(float (*dst)[128], const float* __restrict__ src)
{
    const int tid = threadIdx.x;
    #pragma unroll
    for (int j = 0; j < 4; ++j) {
        int gi = j * 256 + tid;          // 0..1023 float4 slots
        int row = gi >> 5;               // 0..31
        int col = (gi & 31) * 4;
        *reinterpret_cast<float4*>(&dst[row][col]) =
            *reinterpret_cast<const float4*>(&src[(size_t)row * DD + col]);
    }
}

// ---------------------------------------------------------------------------
// GEMM, K=128: acc[i][j] += A[rg*4+i][k] * B[k][c4+j]
// A: LDS row-major (broadcast reads within half-wave: conflict-free)
// B: GLOBAL (L1/L2-resident weights), coalesced 512B per half-wave,
//    software-pipelined: B regs for k+4 loaded before FMAs of k.
// ---------------------------------------------------------------------------
#define FMA_STEP(kk, B0, B1, B2, B3)                                              \
    {                                                                             \
        _Pragma("unroll")                                                         \
        for (int i = 0; i < 4; ++i) {                                             \
            float4 av = *reinterpret_cast<const float4*>(&A[rg * 4 + i][kk]);     \
            acc[i][0] += av.x * B0.x; acc[i][1] += av.x * B0.y;                   \
            acc[i][2] += av.x * B0.z; acc[i][3] += av.x * B0.w;                   \
            acc[i][0] += av.y * B1.x; acc[i][1] += av.y * B1.y;                   \
            acc[i][2] += av.y * B1.z; acc[i][3] += av.y * B1.w;                   \
            acc[i][0] += av.z * B2.x; acc[i][1] += av.z * B2.y;                   \
            acc[i][2] += av.z * B2.z; acc[i][3] += av.z * B2.w;                   \
            acc[i][0] += av.w * B3.x; acc[i][1] += av.w * B3.y;                   \
            acc[i][2] += av.w * B3.z; acc[i][3] += av.w * B3.w;                   \
        }                                                                         \
    }

__device__ __forceinline__ void gemm128_pf(const float (*A)[128], const float* __restrict__ Bg,
                                           int bStrideF, int rg, int c4, float acc[4][4])
{
    const float* bp = Bg + c4;
    float4 nb0 = *reinterpret_cast<const float4*>(bp);
    float4 nb1 = *reinterpret_cast<const float4*>(bp + bStrideF);
    float4 nb2 = *reinterpret_cast<const float4*>(bp + 2 * (size_t)bStrideF);
    float4 nb3 = *reinterpret_cast<const float4*>(bp + 3 * (size_t)bStrideF);
    #pragma unroll 4
    for (int k = 0; k < 124; k += 4) {
        float4 b0 = nb0, b1 = nb1, b2 = nb2, b3 = nb3;
        bp += 4 * (size_t)bStrideF;
        nb0 = *reinterpret_cast<const float4*>(bp);
        nb1 = *reinterpret_cast<const float4*>(bp + bStrideF);
        nb2 = *reinterpret_cast<const float4*>(bp + 2 * (size_t)bStrideF);
        nb3 = *reinterpret_cast<const float4*>(bp + 3 * (size_t)bStrideF);
        FMA_STEP(k, b0, b1, b2, b3);
    }
    FMA_STEP(124, nb0, nb1, nb2, nb3);
}

// ---------------------------------------------------------------------------
// attention logits + 2-edge segment softmax for a 32-row statement-aligned tile
// ---------------------------------------------------------------------------
__device__ __forceinline__ void attn32(const float (*hsv)[128],
                                       const float* avs, const float* avd,
                                       float* als, float* ald, float* aSw, float* aNw)
{
    const int tid = threadIdx.x;
    if (tid < 64) {
        int r = tid & 31;
        const float* av = (tid < 32) ? avs : avd;
        float s = 0.f;
        #pragma unroll 8
        for (int cc = 0; cc < 128; ++cc) {
            int c = (cc + r) & 127;       // 32 lanes -> 32 distinct banks: free
            s += hsv[r][c] * av[c];
        }
        if (tid < 32) als[r] = s; else ald[r] = s;
    }
    __syncthreads();
    if (tid < 32) {
        int r = tid;
        float es = als[r] + ald[r];
        es = es > 0.f ? es : 0.2f * es;
        float aSv = 1.f, aNv = 0.f;
        if ((r & 15) != 15) {
            float en = als[r + 1] + ald[r];
            en = en > 0.f ? en : 0.2f * en;
            float m = fmaxf(es, en);
            float xse = expf(es - m), xne = expf(en - m);
            float den = xse + xne;
            aSv = xse / den; aNv = xne / den;
        }
        aSw[r] = aSv; aNw[r] = aNv;
    }
    __syncthreads();
}

// ---------------------------------------------------------------------------
// Pass 1: layer-0 forward for BN0 statistics only.
// Grid 4096 x 256 thr; 2 phases of 32 statement-aligned rows.
// LDS ~37.5KB -> 4 blocks/CU (16 waves).
// ---------------------------------------------------------------------------
__global__ __launch_bounds__(256, 4)
void gat0_stats(const float* __restrict__ x, const float* __restrict__ W0,
                const float* __restrict__ as0, const float* __restrict__ ad0,
                const float* __restrict__ b0, float* __restrict__ pA0)
{
    __shared__ float xs[32][128];
    __shared__ float hs[32][128];
    __shared__ float avs[128], avd[128];
    __shared__ float als[32], ald[32], aSw[32], aNw[32];
    __shared__ float bns[8][128];

    const int tid = threadIdx.x;
    const int bid = blockIdx.x;
    const int rg = tid >> 5;          // 0..7 -> rows rg*4..rg*4+3
    const int c4 = (tid & 31) * 4;

    float psum[HH][4], qsum[HH][4];
    #pragma unroll
    for (int h = 0; h < HH; ++h)
        #pragma unroll
        for (int j = 0; j < 4; ++j) { psum[h][j] = 0.f; qsum[h][j] = 0.f; }

    for (int t = 0; t < 2; ++t) {
        const size_t rb = (size_t)bid * 64 + (size_t)t * 32;
        __syncthreads();                   // previous phase's xs readers done
        stage32x128(xs, x + rb * DD);
        __syncthreads();

        for (int h = 0; h < HH; ++h) {
            float acc[4][4];
            #pragma unroll
            for (int i = 0; i < 4; ++i)
                #pragma unroll
                for (int j = 0; j < 4; ++j) acc[i][j] = 0.f;

            gemm128_pf(xs, W0 + h * DD, HD, rg, c4, acc);

            __syncthreads();               // prior hs readers done
            #pragma unroll
            for (int i = 0; i < 4; ++i) {
                float4 v; v.x = acc[i][0]; v.y = acc[i][1]; v.z = acc[i][2]; v.w = acc[i][3];
                *reinterpret_cast<float4*>(&hs[rg * 4 + i][c4]) = v;
            }
            if (tid < 128) { avs[tid] = as0[h * DD + tid]; avd[tid] = ad0[h * DD + tid]; }
            __syncthreads();
            attn32(hs, avs, avd, als, ald, aSw, aNw);

            float4 bb = *reinterpret_cast<const float4*>(&b0[h * DD + c4]);
            #pragma unroll
            for (int i = 0; i < 4; ++i) {
                int r = rg * 4 + i;
                float4 hv = *reinterpret_cast<const float4*>(&hs[r][c4]);
                float4 hx = hv;
                if ((r & 15) != 15) hx = *reinterpret_cast<const float4*>(&hs[r + 1][c4]);
                float a_s = aSw[r], a_n = aNw[r];
                float o0 = fmaxf(a_s * hv.x + a_n * hx.x + bb.x, 0.f);
                float o1 = fmaxf(a_s * hv.y + a_n * hx.y + bb.y, 0.f);
                float o2 = fmaxf(a_s * hv.z + a_n * hx.z + bb.z, 0.f);
                float o3 = fmaxf(a_s * hv.w + a_n * hx.w + bb.w, 0.f);
                psum[h][0] += o0; qsum[h][0] += o0 * o0;
                psum[h][1] += o1; qsum[h][1] += o1 * o1;
                psum[h][2] += o2; qsum[h][2] += o2 * o2;
                psum[h][3] += o3; qsum[h][3] += o3 * o3;
            }
        }
    }

    // flush BN0 partials per head
    for (int h = 0; h < HH; ++h) {
        __syncthreads();
        #pragma unroll
        for (int j = 0; j < 4; ++j) {
            float s = psum[h][j] + __shfl_down(psum[h][j], 32);
            float q = qsum[h][j] + __shfl_down(qsum[h][j], 32);
            if ((tid & 63) < 32) {
                int w = tid >> 6;
                bns[w][c4 + j] = s;
                bns[4 + w][c4 + j] = q;
            }
        }
        __syncthreads();
        if (tid < 128) {
            float s = bns[0][tid] + bns[1][tid] + bns[2][tid] + bns[3][tid];
            float q = bns[4][tid] + bns[5][tid] + bns[6][tid] + bns[7][tid];
            size_t idx = ((size_t)bid * HD + h * DD + tid) * 2;
            pA0[idx] = s; pA0[idx + 1] = q;
        }
    }
}

// ---------------------------------------------------------------------------
// Pass 3: recompute layer-0 (BN0 applied), interleaved layer-1 GEMM per head,
// layer-1 attention, write r1 + BN1 partials. 2 phases of 32 rows.
// ---------------------------------------------------------------------------
__global__ __launch_bounds__(256, 4)
void gat1_recomp(const float* __restrict__ x, const float* __restrict__ W0,
                 const float* __restrict__ as0, const float* __restrict__ ad0,
                 const float* __restrict__ b0, const float* __restrict__ sc0,
                 const float* __restrict__ sh0, const float* __restrict__ W1,
                 const float* __restrict__ as1, const float* __restrict__ ad1,
                 const float* __restrict__ b1,
                 float* __restrict__ r1, float* __restrict__ pA1)
{
    __shared__ float xs[32][128];
    __shared__ float hs[32][128];
    __shared__ float avs[128], avd[128];
    __shared__ float als[32], ald[32], aSw[32], aNw[32];
    __shared__ float bns[8][128];

    const int tid = threadIdx.x;
    const int bid = blockIdx.x;
    const int rg = tid >> 5;
    const int c4 = (tid & 31) * 4;

    float ps1[4] = {0, 0, 0, 0}, pq1[4] = {0, 0, 0, 0};

    for (int t = 0; t < 2; ++t) {
        const size_t rb = (size_t)bid * 64 + (size_t)t * 32;
        __syncthreads();                   // previous phase's xs/hs readers done
        stage32x128(xs, x + rb * DD);
        __syncthreads();

        float acc2[4][4];                  // layer-1 accumulator (K=384)
        #pragma unroll
        for (int i = 0; i < 4; ++i)
            #pragma unroll
            for (int j = 0; j < 4; ++j) acc2[i][j] = 0.f;

        for (int h = 0; h < HH; ++h) {
            // ---- layer-0 GEMM for head h ----
            float acc[4][4];
            #pragma unroll
            for (int i = 0; i < 4; ++i)
                #pragma unroll
                for (int j = 0; j < 4; ++j) acc[i][j] = 0.f;

            gemm128_pf(xs, W0 + h * DD, HD, rg, c4, acc);

            __syncthreads();               // prev head's GEMM1 reads of hs done
            #pragma unroll
            for (int i = 0; i < 4; ++i) {
                float4 v; v.x = acc[i][0]; v.y = acc[i][1]; v.z = acc[i][2]; v.w = acc[i][3];
                *reinterpret_cast<float4*>(&hs[rg * 4 + i][c4]) = v;
            }
            if (tid < 128) { avs[tid] = as0[h * DD + tid]; avd[tid] = ad0[h * DD + tid]; }
            __syncthreads();
            attn32(hs, avs, avd, als, ald, aSw, aNw);

            // ---- aggregate + b0 + relu + BN0 -> regs ----
            float4 bb  = *reinterpret_cast<const float4*>(&b0[h * DD + c4]);
            float4 scv = *reinterpret_cast<const float4*>(&sc0[h * DD + c4]);
            float4 shv = *reinterpret_cast<const float4*>(&sh0[h * DD + c4]);
            float rr[4][4];
            #pragma unroll
            for (int i = 0; i < 4; ++i) {
                int r = rg * 4 + i;
                float4 hv = *reinterpret_cast<const float4*>(&hs[r][c4]);
                float4 hx = hv;
                if ((r & 15) != 15) hx = *reinterpret_cast<const float4*>(&hs[r + 1][c4]);
                float a_s = aSw[r], a_n = aNw[r];
                rr[i][0] = fmaxf(a_s * hv.x + a_n * hx.x + bb.x, 0.f) * scv.x + shv.x;
                rr[i][1] = fmaxf(a_s * hv.y + a_n * hx.y + bb.y, 0.f) * scv.y + shv.y;
                rr[i][2] = fmaxf(a_s * hv.z + a_n * hx.z + bb.z, 0.f) * scv.z + shv.z;
                rr[i][3] = fmaxf(a_s * hv.w + a_n * hx.w + bb.w, 0.f) * scv.w + shv.w;
            }
            __syncthreads();               // all reads of hs done
            #pragma unroll
            for (int i = 0; i < 4; ++i) {
                float4 v; v.x = rr[i][0]; v.y = rr[i][1]; v.z = rr[i][2]; v.w = rr[i][3];
                *reinterpret_cast<float4*>(&hs[rg * 4 + i][c4]) = v;
            }
            __syncthreads();

            // ---- layer-1 partial GEMM over k chunk [h*128, h*128+128) ----
            gemm128_pf(hs, W1 + (size_t)(h * DD) * DD, DD, rg, c4, acc2);
        }

        // ---- layer-1 attention ----
        __syncthreads();                   // GEMM1 reads of hs done
        #pragma unroll
        for (int i = 0; i < 4; ++i) {
            float4 v; v.x = acc2[i][0]; v.y = acc2[i][1]; v.z = acc2[i][2]; v.w = acc2[i][3];
            *reinterpret_cast<float4*>(&hs[rg * 4 + i][c4]) = v;
        }
        if (tid < 128) { avs[tid] = as1[tid]; avd[tid] = ad1[tid]; }
        __syncthreads();
        attn32(hs, avs, avd, als, ald, aSw, aNw);

        // aggregate + b1 + relu -> r1 + BN1 partials
        float4 bb1 = *reinterpret_cast<const float4*>(&b1[c4]);
        #pragma unroll
        for (int i = 0; i < 4; ++i) {
            int r = rg * 4 + i;
            float4 hv = *reinterpret_cast<const float4*>(&hs[r][c4]);
            float4 hx = hv;
            if ((r & 15) != 15) hx = *reinterpret_cast<const float4*>(&hs[r + 1][c4]);
            float a_s = aSw[r], a_n = aNw[r];
            float o0 = fmaxf(a_s * hv.x + a_n * hx.x + bb1.x, 0.f);
            float o1 = fmaxf(a_s * hv.y + a_n * hx.y + bb1.y, 0.f);
            float o2 = fmaxf(a_s * hv.z + a_n * hx.z + bb1.z, 0.f);
            float o3 = fmaxf(a_s * hv.w + a_n * hx.w + bb1.w, 0.f);
            float4 ov; ov.x = o0; ov.y = o1; ov.z = o2; ov.w = o3;
            *reinterpret_cast<float4*>(&r1[(rb + r) * DD + c4]) = ov;
            ps1[0] += o0; pq1[0] += o0 * o0;
            ps1[1] += o1; pq1[1] += o1 * o1;
            ps1[2] += o2; pq1[2] += o2 * o2;
            ps1[3] += o3; pq1[3] += o3 * o3;
        }
    }

    // flush BN1 partials
    __syncthreads();
    #pragma unroll
    for (int j = 0; j < 4; ++j) {
        float s = ps1[j] + __shfl_down(ps1[j], 32);
        float q = pq1[j] + __shfl_down(pq1[j], 32);
        if ((tid & 63) < 32) {
            int w = tid >> 6;
            bns[w][c4 + j] = s;
            bns[4 + w][c4 + j] = q;
        }
    }
    __syncthreads();
    if (tid < 128) {
        float s = bns[0][tid] + bns[1][tid] + bns[2][tid] + bns[3][tid];
        float q = bns[4][tid] + bns[5][tid] + bns[6][tid] + bns[7][tid];
        size_t idx = ((size_t)bid * DD + tid) * 2;
        pA1[idx] = s; pA1[idx + 1] = q;
    }
}

// ---------------------------------------------------------------------------
// BN stat reduction: per column, sum partials -> scale/shift
// ---------------------------------------------------------------------------
__global__ __launch_bounds__(256)
void bn_reduce(const float* __restrict__ pA, int nblk, int ncol, float invN,
               const float* __restrict__ g, const float* __restrict__ be,
               float* __restrict__ sc, float* __restrict__ sh)
{
    __shared__ float rs[256], rq[256];
    int col = blockIdx.x, tid = threadIdx.x;
    float s = 0.f, q = 0.f;
    for (int i = tid; i < nblk; i += 256) {
        size_t idx = ((size_t)i * ncol + col) * 2;
        s += pA[idx]; q += pA[idx + 1];
    }
    rs[tid] = s; rq[tid] = q;
    __syncthreads();
    for (int o = 128; o > 0; o >>= 1) {
        if (tid < o) { rs[tid] += rs[tid + o]; rq[tid] += rq[tid + o]; }
        __syncthreads();
    }
    if (tid == 0) {
        float mu  = rs[0] * invN;
        float var = fmaxf(rq[0] * invN - mu * mu, 0.f);
        float inv = 1.0f / sqrtf(var + EPSV);
        float scv = g[col] * inv;
        sc[col] = scv;
        sh[col] = be[col] - mu * scv;
    }
}

__global__ __launch_bounds__(128)
void compute_pn(const float* __restrict__ p, float* __restrict__ pn)
{
    __shared__ float rs[128];
    int t = threadIdx.x;
    float v = p[t];
    rs[t] = v * v;
    __syncthreads();
    for (int o = 64; o > 0; o >>= 1) {
        if (t < o) rs[t] += rs[t + o];
        __syncthreads();
    }
    float nrm = sqrtf(rs[0]) + 1e-16f;
    pn[t] = v / nrm;
}

// ---------------------------------------------------------------------------
// Pass 5: per-statement BN1 affine + score + top-8 + tanh-weighted relu mean
// + MLP 128->32->128
// ---------------------------------------------------------------------------
__global__ __launch_bounds__(128)
void pool_mlp(const float* __restrict__ r1, const float* __restrict__ sc1,
              const float* __restrict__ sh1, const float* __restrict__ pn,
              const float* __restrict__ mW1, const float* __restrict__ mb1,
              const float* __restrict__ mW2, const float* __restrict__ mb2,
              float* __restrict__ out)
{
    __shared__ float hf[16][136];
    __shared__ float sv[16];
    __shared__ float tv[16];
    __shared__ float pooled[128];
    __shared__ float y1[32];
    int tid = threadIdx.x;
    int sid = blockIdx.x;
    float scv = sc1[tid], shv = sh1[tid];
    const float* base = r1 + (size_t)sid * TT * DD;
    #pragma unroll
    for (int i = 0; i < 16; ++i)
        hf[i][tid] = base[i * DD + tid] * scv + shv;
    __syncthreads();

    {
        int r = tid >> 3, q = tid & 7;
        float s = 0.f;
        #pragma unroll
        for (int cc = 0; cc < 16; ++cc) {
            int c = q + cc * 8;
            s += hf[r][c] * pn[c];
        }
        s += __shfl_down(s, 4, 8);
        s += __shfl_down(s, 2, 8);
        s += __shfl_down(s, 1, 8);
        if (q == 0) sv[r] = s;
    }
    __syncthreads();

    if (tid < 16) {
        float si = sv[tid];
        int rank = 0;
        #pragma unroll
        for (int u = 0; u < 16; ++u) {
            float su = sv[u];
            rank += (su > si || (su == si && u < tid)) ? 1 : 0;
        }
        tv[tid] = (rank < 8) ? tanhf(si) : 0.f;
    }
    __syncthreads();

    {
        float a = 0.f;
        #pragma unroll
        for (int rr = 0; rr < 16; ++rr)
            a += fmaxf(hf[rr][tid] * tv[rr], 0.f);
        pooled[tid] = a * 0.125f;
    }
    __syncthreads();

    {
        int j = tid >> 2, q = tid & 3;
        float a = 0.f;
        #pragma unroll
        for (int cc = 0; cc < 32; ++cc) {
            int c = q + cc * 4;
            a += pooled[c] * mW1[(size_t)c * 32 + j];
        }
        a += __shfl_down(a, 2, 4);
        a += __shfl_down(a, 1, 4);
        if (q == 0) y1[j] = fmaxf(a + mb1[j], 0.f);
    }
    __syncthreads();

    {
        float o = mb2[tid];
        #pragma unroll
        for (int j = 0; j < 32; ++j) o += y1[j] * mW2[j * 128 + tid];
        out[(size_t)sid * 128 + tid] = o;
    }
}

// ===========================================================================
extern "C" void kernel_launch(void* const* d_in, const int* in_sizes, int n_in,
                              void* d_out, int out_size, void* d_ws, size_t ws_size,
                              hipStream_t stream)
{
    (void)in_sizes; (void)n_in; (void)out_size; (void)ws_size;
    const float* x   = (const float*)d_in[0];
    const float* W0  = (const float*)d_in[1];
    const float* as0 = (const float*)d_in[2];
    const float* ad0 = (const float*)d_in[3];
    const float* b0  = (const float*)d_in[4];
    const float* g0  = (const float*)d_in[5];
    const float* be0 = (const float*)d_in[6];
    const float* W1  = (const float*)d_in[7];
    const float* as1 = (const float*)d_in[8];
    const float* ad1 = (const float*)d_in[9];
    const float* b1  = (const float*)d_in[10];
    const float* g1  = (const float*)d_in[11];
    const float* be1 = (const float*)d_in[12];
    const float* p   = (const float*)d_in[13];
    const float* mW1 = (const float*)d_in[14];
    const float* mb1 = (const float*)d_in[15];
    const float* mW2 = (const float*)d_in[16];
    const float* mb2 = (const float*)d_in[17];
    float* out = (float*)d_out;

    // ws layout (~151 MB; ws >= 156 MB proven by round-2 RECOMP pass)
    const size_t R1B  = (size_t)N_NODES * DD * 4;     // 134,217,728
    const size_t PA0B = 4096ull * HD * 2 * 4;         //  12,582,912
    const size_t PA1B = 4096ull * DD * 2 * 4;         //   4,194,304

    char* ws = (char*)d_ws;
    float* r1  = (float*)ws;
    float* pA0 = (float*)(ws + R1B);
    float* pA1 = (float*)(ws + R1B + PA0B);
    float* vec = (float*)(ws + R1B + PA0B + PA1B);
    float* sc0 = vec;            // 512 floats each slot
    float* sh0 = vec + 512;
    float* sc1 = vec + 1024;
    float* sh1 = vec + 1536;
    float* pn  = vec + 2048;

    const float invN = 1.0f / (float)N_NODES;

    gat0_stats<<<N_NODES / 64, 256, 0, stream>>>(x, W0, as0, ad0, b0, pA0);
    bn_reduce<<<HD, 256, 0, stream>>>(pA0, N_NODES / 64, HD, invN, g0, be0, sc0, sh0);
    compute_pn<<<1, 128, 0, stream>>>(p, pn);
    gat1_recomp<<<N_NODES / 64, 256, 0, stream>>>(x, W0, as0, ad0, b0, sc0, sh0,
                                                  W1, as1, ad1, b1, r1, pA1);
    bn_reduce<<<DD, 256, 0, stream>>>(pA1, N_NODES / 64, DD, invN, g1, be1, sc1, sh1);
    pool_mlp<<<SSTMT, 128, 0, stream>>>(r1, sc1, sh1, pn, mW1, mb1, mW2, mb2, out);
}